// Round 4
// baseline (9552.216 us; speedup 1.0000x reference)
//
#include <hip/hip_runtime.h>

#define NODES 32768
#define EDGES 524288
#define BGR   64
#define LSEQ  512
#define DEMB  256
#define HDIM  512

typedef unsigned short u16;
typedef unsigned int   u32;
typedef unsigned long long u64;
typedef __attribute__((ext_vector_type(8))) short short8;
typedef __attribute__((ext_vector_type(4))) float f32x4;

__device__ __forceinline__ float bf2f(u16 u){ u32 x = ((u32)u)<<16; float f; __builtin_memcpy(&f,&x,4); return f; }
__device__ __forceinline__ u16 f2bf(float f){ u32 x; __builtin_memcpy(&x,&f,4); u32 r = x + 0x7fffu + ((x>>16)&1u); return (u16)(r>>16); }
__device__ __forceinline__ float lo16(u32 u){ u32 x = u<<16; float f; __builtin_memcpy(&f,&x,4); return f; }
__device__ __forceinline__ float hi16(u32 u){ u32 x = u & 0xffff0000u; float f; __builtin_memcpy(&f,&x,4); return f; }
__device__ __forceinline__ u32 pack2(float a, float b){ return (u32)f2bf(a) | ((u32)f2bf(b)<<16); }

// batched fast poll: 8 tagged u64 via L2-coherent loads (sc0 = bypass L1, served by XCD L2)
__device__ __forceinline__ void poll8_sc0(const u64* p, u64* v){
  asm volatile(
    "global_load_dwordx2 %0, %8, off sc0\n\t"
    "global_load_dwordx2 %1, %8, off offset:8 sc0\n\t"
    "global_load_dwordx2 %2, %8, off offset:16 sc0\n\t"
    "global_load_dwordx2 %3, %8, off offset:24 sc0\n\t"
    "global_load_dwordx2 %4, %8, off offset:32 sc0\n\t"
    "global_load_dwordx2 %5, %8, off offset:40 sc0\n\t"
    "global_load_dwordx2 %6, %8, off offset:48 sc0\n\t"
    "global_load_dwordx2 %7, %8, off offset:56 sc0\n\t"
    "s_waitcnt vmcnt(0)"
    : "=&v"(v[0]), "=&v"(v[1]), "=&v"(v[2]), "=&v"(v[3]),
      "=&v"(v[4]), "=&v"(v[5]), "=&v"(v[6]), "=&v"(v[7])
    : "v"(p)
    : "memory");
}

// ---------------- utility kernels ----------------

__global__ void zero_i32(int* p, int n){
  int i = blockIdx.x*256 + threadIdx.x;
  if (i < n) p[i] = 0;
}

// out[n*K + k] = bf16(in[k*N + n])   (in is [K][N] row-major)
__global__ void transpose_cast(const float* __restrict__ in, u16* __restrict__ out, int K, int N){
  int i = blockIdx.x*256 + threadIdx.x;
  if (i < N*K){ int n = i / K, k = i - n*K; out[i] = f2bf(in[(size_t)k*N + n]); }
}

__global__ void cast_bf(const float* __restrict__ in, u16* __restrict__ out, int n){
  int i = blockIdx.x*256 + threadIdx.x;
  if (i < n) out[i] = f2bf(in[i]);
}

__global__ void count_indeg(const int* __restrict__ dst, int* __restrict__ indeg){
  int e = blockIdx.x*256 + threadIdx.x;
  if (e < EDGES) atomicAdd(&indeg[dst[e]], 1);
}

__global__ void compute_dinv(const int* __restrict__ indeg, float* __restrict__ dinv){
  int i = blockIdx.x*256 + threadIdx.x;
  if (i < NODES) dinv[i] = rsqrtf((float)(indeg[i] + 1));  // +1 self loop
}

// single-block exclusive scan of indeg -> row_ptr (+cursor copy). N = 32768 = 1024*32
__global__ __launch_bounds__(1024) void scan_csr(const int* __restrict__ indeg,
                                                 int* __restrict__ row_ptr,
                                                 int* __restrict__ cursor){
  __shared__ int part[1024];
  int tid = threadIdx.x, base = tid*32;
  int loc[32]; int s = 0;
  for (int i=0;i<32;i++){ loc[i] = s; s += indeg[base+i]; }
  part[tid] = s; __syncthreads();
  for (int off=1; off<1024; off<<=1){
    int v = part[tid]; int add = (tid>=off) ? part[tid-off] : 0;
    __syncthreads(); part[tid] = v + add; __syncthreads();
  }
  int offt = (tid==0) ? 0 : part[tid-1];
  for (int i=0;i<32;i++){ int v = offt + loc[i]; row_ptr[base+i] = v; cursor[base+i] = v; }
}

__global__ void fill_csr(const int* __restrict__ src, const int* __restrict__ dst,
                         int* __restrict__ cursor, int* __restrict__ csr_src){
  int e = blockIdx.x*256 + threadIdx.x;
  if (e < EDGES){ int d = dst[e]; int p = atomicAdd(&cursor[d], 1); csr_src[p] = src[e]; }
}

// ---------------- GCN aggregation ----------------
// bf16 embedding table (precast): halves gather traffic, ~fits XCD L2.
__global__ __launch_bounds__(256) void agg_emb(const int* __restrict__ x, const u16* __restrict__ embb,
    const float* __restrict__ dinv, const int* __restrict__ row_ptr, const int* __restrict__ indeg,
    const int* __restrict__ csr_src, u16* __restrict__ out){
  int node = blockIdx.x*4 + (threadIdx.x>>6);
  int lane = threadIdx.x & 63;
  float di = dinv[node];
  int xi = x[node];
  u64 hv = *(const u64*)(embb + (size_t)xi*DEMB + lane*4);
  u32 h0 = (u32)hv, h1 = (u32)(hv>>32);
  float a0 = lo16(h0)*di, a1 = hi16(h0)*di, a2 = lo16(h1)*di, a3 = hi16(h1)*di;
  int st = row_ptr[node], cn = indeg[node];
  for (int p = st; p < st+cn; p++){
    int s = csr_src[p];
    float ws = dinv[s];
    u64 v = *(const u64*)(embb + (size_t)x[s]*DEMB + lane*4);
    u32 w0 = (u32)v, w1 = (u32)(v>>32);
    a0 += lo16(w0)*ws; a1 += hi16(w0)*ws; a2 += lo16(w1)*ws; a3 += hi16(w1)*ws;
  }
  u64 pv = (u64)pack2(a0*di,a1*di) | ((u64)pack2(a2*di,a3*di)<<32);
  *(u64*)(out + (size_t)node*DEMB + lane*4) = pv;
}

__global__ __launch_bounds__(256) void agg_h(const u16* __restrict__ hin, const float* __restrict__ dinv,
    const int* __restrict__ row_ptr, const int* __restrict__ indeg,
    const int* __restrict__ csr_src, u16* __restrict__ out){
  int node = blockIdx.x*4 + (threadIdx.x>>6);
  int lane = threadIdx.x & 63;
  float di = dinv[node];
  float a[8];
  uint4 hv = *((const uint4*)(hin + (size_t)node*HDIM) + lane);
  a[0]=lo16(hv.x)*di; a[1]=hi16(hv.x)*di; a[2]=lo16(hv.y)*di; a[3]=hi16(hv.y)*di;
  a[4]=lo16(hv.z)*di; a[5]=hi16(hv.z)*di; a[6]=lo16(hv.w)*di; a[7]=hi16(hv.w)*di;
  int st = row_ptr[node], cn = indeg[node];
  for (int p = st; p < st+cn; p++){
    int s = csr_src[p];
    float ws = dinv[s];
    uint4 v = *((const uint4*)(hin + (size_t)s*HDIM) + lane);
    a[0]+=lo16(v.x)*ws; a[1]+=hi16(v.x)*ws; a[2]+=lo16(v.y)*ws; a[3]+=hi16(v.y)*ws;
    a[4]+=lo16(v.z)*ws; a[5]+=hi16(v.z)*ws; a[6]+=lo16(v.w)*ws; a[7]+=hi16(v.w)*ws;
  }
  uint4 o; o.x=pack2(a[0]*di,a[1]*di); o.y=pack2(a[2]*di,a[3]*di);
  o.z=pack2(a[4]*di,a[5]*di); o.w=pack2(a[6]*di,a[7]*di);
  *(uint4*)(out + (size_t)node*HDIM + lane*8) = o;
}

// ---------------- bf16 MFMA GEMM: C[M,N] = act(A[M,K] @ BT[N,K]^T + bias) ----------------
#define BM 128
#define BN 128
#define BKK 32
__global__ __launch_bounds__(256) void gemm_bt(const u16* __restrict__ A, const u16* __restrict__ BT,
    const float* __restrict__ bias, u16* __restrict__ C, int M, int N, int K, int relu){
  __shared__ u16 aS[BM][BKK+8];
  __shared__ u16 bS[BN][BKK+8];
  int tid = threadIdx.x;
  int m0 = blockIdx.y * BM, n0 = blockIdx.x * BN;
  int lane = tid & 63, w = tid >> 6;
  int wm = w >> 1, wn = w & 1;
  f32x4 acc[4][4];
  for (int i=0;i<4;i++) for (int j=0;j<4;j++) acc[i][j] = (f32x4)0.0f;

  int r  = tid >> 1;
  int cc = (tid & 1) * 16;
  const u16* Ag = A + (size_t)(m0 + r) * K + cc;
  const u16* Bg = BT + (size_t)(n0 + r) * K + cc;
  int l15 = lane & 15, q8 = (lane >> 4) * 8;

  for (int k0 = 0; k0 < K; k0 += BKK) {
    uint4 av0 = *(const uint4*)(Ag + k0);
    uint4 av1 = *(const uint4*)(Ag + k0 + 8);
    uint4 bv0 = *(const uint4*)(Bg + k0);
    uint4 bv1 = *(const uint4*)(Bg + k0 + 8);
    *(uint4*)&aS[r][cc]   = av0; *(uint4*)&aS[r][cc+8] = av1;
    *(uint4*)&bS[r][cc]   = bv0; *(uint4*)&bS[r][cc+8] = bv1;
    __syncthreads();
    short8 af[4], bfr[4];
    for (int i=0;i<4;i++) af[i]  = *(const short8*)&aS[wm*64 + i*16 + l15][q8];
    for (int j=0;j<4;j++) bfr[j] = *(const short8*)&bS[wn*64 + j*16 + l15][q8];
    for (int i=0;i<4;i++)
      for (int j=0;j<4;j++)
        acc[i][j] = __builtin_amdgcn_mfma_f32_16x16x32_bf16(af[i], bfr[j], acc[i][j], 0, 0, 0);
    __syncthreads();
  }
  int q = lane >> 4;
  for (int i=0;i<4;i++) for (int j=0;j<4;j++){
    int col = n0 + wn*64 + j*16 + l15;
    float bval = bias[col];
    for (int rr=0; rr<4; rr++){
      int row = m0 + wm*64 + i*16 + q*4 + rr;
      float v = acc[i][j][rr] + bval;
      if (relu) v = fmaxf(v, 0.f);
      C[(size_t)row * N + col] = f2bf(v);
    }
  }
}

// ---------------- GRU R9: XCD-local teams + dual-path tagged exchange ----------------
// R8 proved the exchange is LATENCY-bound (250x less poll traffic -> same time): the chain is
// 2-3 serialized MALL round trips because team WGs span all 8 XCDs. R9 remaps teams to be
// XCD-local under the round-robin dispatch heuristic (XCD ~= blockIdx%8): grid=128,
// team g = blockIdx&7 (g<4 active), slice j = blockIdx>>3 -> 16 WGs of a team on ONE XCD
// (1 WG/CU by LDS, co-resident). Exchange then runs at XCD-L2 latency: writers publish the
// R5 tagged u64 ((t+1)<<32 | bf16pair) to BOTH a fast region (workgroup-scope store = plain
// global_store, L2-visible) and an agent region (MALL, R5's proven protocol). Readers poll
// the fast region with sc0 loads (bypass L1, hit shared L2); on cap-out fall back to the
// agent poll. Placement is a heuristic only: per-thread sticky fallback (2 strikes) keeps
// correctness placement-independent; caps keep any failure a wrong-number, never a hang.
// Tag/payload share one naturally-aligned 8B access (single-copy atomic, as in R5).
__global__ __launch_bounds__(512) void gru_kernel(const u16* __restrict__ gi,
    const float* __restrict__ Whh, const float* __restrict__ bhh,
    float* __restrict__ graph_emb, u64* __restrict__ fdb_base, u64* __restrict__ adb_base){
  __shared__ u16  w_lds[96*520];
  __shared__ u16  h_lds[16*520];
  __shared__ float gh_lds[16*100];

  int g = blockIdx.x & 7, j = blockIdx.x >> 3;
  if (g >= 4) return;                    // 64 idle blocks exit (teams 4..7 unused)
  int tid = threadIdx.x;
  int wave = tid >> 6;

  // load Whh slice: rows {j*32..+32} of each gate, bf16 into LDS (padded stride 520)
  for (int idx = tid; idx < 96*512; idx += 512){
    int rr = idx >> 9, c = idx & 511;
    int grow = (rr >> 5) * 512 + j*32 + (rr & 31);
    w_lds[rr*520 + c] = f2bf(Whh[(size_t)grow*512 + c]);
  }
  for (int idx = tid; idx < 16*520; idx += 512) h_lds[idx] = 0;

  int b = tid >> 5, hh = tid & 31;     // (batch-in-group, h-in-slice)
  int bg = g*16 + b;
  int c_r = j*32 + hh, c_z = 512 + j*32 + hh, c_n = 1024 + j*32 + hh;
  float bias_r = bhh[c_r], bias_z = bhh[c_z], bias_n = bhh[c_n];
  const u16* gi_row = gi + (size_t)bg * LSEQ * 1536;
  float h_prev = 0.f, accm = 0.f;
  int l15 = tid & 15, q8 = ((tid & 63)>>4)*8, qr = ((tid & 63)>>4)*4;

  u64* fdb = fdb_base + (size_t)g * 8192;   // [parity][16 b][256 slots] u64 (fast / L2)
  u64* adb = adb_base + (size_t)g * 8192;   // same layout (agent / MALL)
  // pipeline: gate inputs for step t held in registers
  u16 g_r = gi_row[c_r], g_z = gi_row[c_z], g_n = gi_row[c_n];

  bool usefast = true;
  int  strikes = 0;

  __syncthreads();

  for (int t = 0; t < LSEQ; t++){
    u32 tag = (u32)(t + 1);
    int par = t & 1;

    // ---- matvec: gh = h @ Whh_slice^T (waves 0-5) ----
    if (wave < 6){
      f32x4 acc0 = (f32x4)0.0f, acc1 = (f32x4)0.0f;
      const u16* wrow = &w_lds[(wave*16 + l15)*520];
      const u16* hrow = &h_lds[l15*520];
      #pragma unroll
      for (int k0 = 0; k0 < 256; k0 += 32){
        acc0 = __builtin_amdgcn_mfma_f32_16x16x32_bf16(*(const short8*)(hrow + k0 + q8),
                                                       *(const short8*)(wrow + k0 + q8), acc0, 0, 0, 0);
        acc1 = __builtin_amdgcn_mfma_f32_16x16x32_bf16(*(const short8*)(hrow + 256 + k0 + q8),
                                                       *(const short8*)(wrow + 256 + k0 + q8), acc1, 0, 0, 0);
      }
      f32x4 acc = acc0 + acc1;
      int col = wave*16 + l15;
      #pragma unroll
      for (int rr2 = 0; rr2 < 4; rr2++) gh_lds[(qr + rr2)*100 + col] = acc[rr2];
    }
    __syncthreads();                       // B1: gh ready

    // ---- gates ----
    float ghr = gh_lds[b*100 + hh]      + bias_r;
    float ghz = gh_lds[b*100 + 32 + hh] + bias_z;
    float ghn = gh_lds[b*100 + 64 + hh] + bias_n;
    float rg = 1.f / (1.f + __expf(-(bf2f(g_r) + ghr)));
    float zg = 1.f / (1.f + __expf(-(bf2f(g_z) + ghz)));
    float pre = bf2f(g_n) + rg * ghn;
    pre = fminf(fmaxf(pre, -20.f), 20.f);
    float e2 = __expf(2.f * pre);
    float nn = (e2 - 1.f) / (e2 + 1.f);
    float h_new = (1.f - zg) * nn + zg * h_prev;
    accm += h_new; h_prev = h_new;

    // ---- dual publish: tagged u64, even lanes (fire-and-forget) ----
    float h_nb = __shfl_xor(h_new, 1, 64);   // partner hh^1 (same wave: lane^1)
    size_t slot = (size_t)(par*16 + b)*256 + j*16 + (hh>>1);
    if ((hh & 1) == 0){
      u64 val = ((u64)tag << 32) | (u64)pack2(h_new, h_nb);
      __hip_atomic_store(fdb + slot, val, __ATOMIC_RELAXED, __HIP_MEMORY_SCOPE_WORKGROUP); // -> L2
      __hip_atomic_store(adb + slot, val, __ATOMIC_RELAXED, __HIP_MEMORY_SCOPE_AGENT);     // -> MALL
    }

    // prefetch next step's gate inputs (overlaps the poll)
    int tn = (t + 1 < LSEQ) ? t + 1 : t;
    const u16* gp2 = gi_row + (size_t)tn * 1536;
    u16 n_r = gp2[c_r], n_z = gp2[c_z], n_n = gp2[c_n];

    // ---- poll own 8 tagged u64: fast (XCD L2) then agent (MALL) fallback ----
    size_t rowoff = (size_t)(par*16 + b)*256 + hh*8;
    const u64* rpf = fdb + rowoff;
    const u64* rpa = adb + rowoff;
    u64 v[8];
    bool got = false;
    if (usefast){
      int cap = (t == 0) ? 1024 : 64;      // t=0 absorbs startup skew
      for (int it = 0; it < cap; it++){
        poll8_sc0(rpf, v);
        bool ok = true;
        #pragma unroll
        for (int i=0;i<8;i++) ok = ok && ((u32)(v[i] >> 32) == tag);
        if (ok){ got = true; break; }
      }
      if (got) strikes = 0;
      else if (++strikes >= 2) usefast = false;   // cross-XCD placement: stick to agent
    }
    if (!got){
      int spins = 0; bool ok;
      do {
        #pragma unroll
        for (int i=0;i<8;i++) v[i] = __hip_atomic_load(rpa + i, __ATOMIC_RELAXED, __HIP_MEMORY_SCOPE_AGENT);
        ok = true;
        #pragma unroll
        for (int i=0;i<8;i++) ok = ok && ((u32)(v[i] >> 32) == tag);
      } while (!ok && ++spins < 16384);    // capped: bug -> wrong numbers, never a hang
    }

    // commit 8 pairs (32 B) into h_lds row b
    u32* hl = (u32*)h_lds + b*260 + hh*8;
    #pragma unroll
    for (int i=0;i<8;i++) hl[i] = (u32)v[i];
    __syncthreads();                       // B2: h_lds ready for next matvec

    g_r = n_r; g_z = n_z; g_n = n_n;
  }
  graph_emb[(size_t)bg*512 + j*32 + hh] = accm * (1.f/512.f);
}

// ---------------- head: relu(g@fc1+b) @ fc2 + b -> sigmoid ----------------
__global__ __launch_bounds__(256) void head(const float* __restrict__ graph_emb, const float* __restrict__ focal,
    const float* __restrict__ fc1w, const float* __restrict__ fc1b,
    const float* __restrict__ fc2w, const float* __restrict__ fc2b, float* __restrict__ out){
  __shared__ float gv[513];
  __shared__ float h1s[512];
  __shared__ float red[4];
  int bq = blockIdx.x, tid = threadIdx.x;
  for (int i = tid; i < 512; i += 256) gv[i] = graph_emb[(size_t)bq*512 + i];
  if (tid == 0) gv[512] = focal[bq];
  __syncthreads();
  for (int c = tid; c < 512; c += 256){
    float acc = fc1b[c];
    for (int k = 0; k < 513; k++) acc += gv[k] * fc1w[(size_t)k*512 + c];
    h1s[c] = fmaxf(acc, 0.f);
  }
  __syncthreads();
  float p = h1s[tid]*fc2w[tid] + h1s[tid+256]*fc2w[tid+256];
  for (int off = 32; off; off >>= 1) p += __shfl_down(p, off, 64);
  if ((tid & 63) == 0) red[tid >> 6] = p;
  __syncthreads();
  if (tid == 0){
    float s = red[0]+red[1]+red[2]+red[3] + fc2b[0];
    out[bq] = 1.f / (1.f + __expf(-s));
  }
}

// ---------------- launch ----------------
extern "C" void kernel_launch(void* const* d_in, const int* in_sizes, int n_in,
                              void* d_out, int out_size, void* d_ws, size_t ws_size,
                              hipStream_t stream){
  const int*   x     = (const int*)d_in[0];
  const int*   edge  = (const int*)d_in[1];
  const int*   srcp  = edge;
  const int*   dstp  = edge + EDGES;
  const float* focal = (const float*)d_in[3];
  const float* emb   = (const float*)d_in[4];
  const float* W1    = (const float*)d_in[5];
  const float* b1    = (const float*)d_in[6];
  const float* W2    = (const float*)d_in[7];
  const float* b2    = (const float*)d_in[8];
  const float* Wih   = (const float*)d_in[9];
  const float* Whh   = (const float*)d_in[10];
  const float* bih   = (const float*)d_in[11];
  const float* bhh   = (const float*)d_in[12];
  const float* fc1w  = (const float*)d_in[13];
  const float* fc1b  = (const float*)d_in[14];
  const float* fc2w  = (const float*)d_in[15];
  const float* fc2b  = (const float*)d_in[16];

  char* ws = (char*)d_ws;
  constexpr size_t H2_OFF    = 0;                      // 32 MB
  constexpr size_t AGG1_OFF  = 33554432;               // 16 MB
  constexpr size_t H1_OFF    = 50331648;               // 32 MB
  constexpr size_t AGG2_OFF  = 83886080;               // 32 MB (embb lives here until agg_h)
  constexpr size_t GI_OFF    = 33554432;               // 96 MB (after aggs dead)
  constexpr size_t MISC      = 134217728;
  constexpr size_t INDEG_OFF = MISC;
  constexpr size_t CNT_OFF   = MISC + 131072;
  constexpr size_t DINV_OFF  = MISC + 131328;
  constexpr size_t ROWPTR_OFF= MISC + 262400;
  constexpr size_t CURSOR_OFF= MISC + 393472;
  constexpr size_t CSR_OFF   = MISC + 524544;
  constexpr size_t W1T_OFF   = MISC + 2621696;
  constexpr size_t W2T_OFF   = MISC + 2883840;
  constexpr size_t WIHB_OFF  = MISC + 3408128;
  constexpr size_t XBUF_OFF  = MISC + 4980992;         // fast region: 4 groups x 8192 u64 = 256 KB
  constexpr size_t XBUF2_OFF = MISC + 5243136;         // agent region: 256 KB
  constexpr size_t GEMB_OFF  = MISC + 5505280;

  int*   indeg  = (int*)(ws + INDEG_OFF);
  float* dinv   = (float*)(ws + DINV_OFF);
  int*   rowptr = (int*)(ws + ROWPTR_OFF);
  int*   cursor = (int*)(ws + CURSOR_OFF);
  int*   csrsrc = (int*)(ws + CSR_OFF);
  u16*   W1T    = (u16*)(ws + W1T_OFF);
  u16*   W2T    = (u16*)(ws + W2T_OFF);
  u16*   WihB   = (u16*)(ws + WIHB_OFF);
  u16*   agg1   = (u16*)(ws + AGG1_OFF);
  u16*   h1     = (u16*)(ws + H1_OFF);
  u16*   agg2   = (u16*)(ws + AGG2_OFF);
  u16*   embb   = (u16*)(ws + AGG2_OFF);               // dead before agg_h writes agg2
  u16*   h2     = (u16*)(ws + H2_OFF);
  u16*   gi     = (u16*)(ws + GI_OFF);
  u64*   fdb    = (u64*)(ws + XBUF_OFF);
  u64*   adb    = (u64*)(ws + XBUF2_OFF);
  float* gemb   = (float*)(ws + GEMB_OFF);

  zero_i32<<<129, 256, 0, stream>>>(indeg, 32768 + 64);
  transpose_cast<<<512, 256, 0, stream>>>(W1, W1T, 256, 512);
  transpose_cast<<<1024, 256, 0, stream>>>(W2, W2T, 512, 512);
  cast_bf<<<3072, 256, 0, stream>>>(Wih, WihB, 1536*512);
  cast_bf<<<10000, 256, 0, stream>>>(emb, embb, 10000*256);
  count_indeg<<<2048, 256, 0, stream>>>(dstp, indeg);
  compute_dinv<<<128, 256, 0, stream>>>(indeg, dinv);
  scan_csr<<<1, 1024, 0, stream>>>(indeg, rowptr, cursor);
  fill_csr<<<2048, 256, 0, stream>>>(srcp, dstp, cursor, csrsrc);
  agg_emb<<<8192, 256, 0, stream>>>(x, embb, dinv, rowptr, indeg, csrsrc, agg1);
  gemm_bt<<<dim3(4, 256), 256, 0, stream>>>(agg1, W1T, b1, h1, NODES, 512, 256, 1);
  agg_h<<<8192, 256, 0, stream>>>(h1, dinv, rowptr, indeg, csrsrc, agg2);
  gemm_bt<<<dim3(4, 256), 256, 0, stream>>>(agg2, W2T, b2, h2, NODES, 512, 512, 1);
  gemm_bt<<<dim3(12, 256), 256, 0, stream>>>(h2, WihB, bih, gi, NODES, 1536, 512, 0);
  gru_kernel<<<128, 512, 0, stream>>>(gi, Whh, bhh, gemb, fdb, adb);
  head<<<64, 256, 0, stream>>>(gemb, focal, fc1w, fc1b, fc2w, fc2b, (float*)d_out);
}

// Round 5
// 9236.530 us; speedup vs baseline: 1.0342x; 1.0342x over previous
//
#include <hip/hip_runtime.h>

#define NODES 32768
#define EDGES 524288
#define BGR   64
#define LSEQ  512
#define DEMB  256
#define HDIM  512

typedef unsigned short u16;
typedef unsigned int   u32;
typedef unsigned long long u64;
typedef __attribute__((ext_vector_type(8))) short short8;
typedef __attribute__((ext_vector_type(4))) float f32x4;

__device__ __forceinline__ float bf2f(u16 u){ u32 x = ((u32)u)<<16; float f; __builtin_memcpy(&f,&x,4); return f; }
__device__ __forceinline__ u16 f2bf(float f){ u32 x; __builtin_memcpy(&x,&f,4); u32 r = x + 0x7fffu + ((x>>16)&1u); return (u16)(r>>16); }
__device__ __forceinline__ float lo16(u32 u){ u32 x = u<<16; float f; __builtin_memcpy(&f,&x,4); return f; }
__device__ __forceinline__ float hi16(u32 u){ u32 x = u & 0xffff0000u; float f; __builtin_memcpy(&f,&x,4); return f; }
__device__ __forceinline__ u32 pack2(float a, float b){ return (u32)f2bf(a) | ((u32)f2bf(b)<<16); }

// batched fast poll: 8 tagged u64 via L2-coherent loads (sc0 = bypass L1, served by XCD L2)
__device__ __forceinline__ void poll8_sc0(const u64* p, u64* v){
  asm volatile(
    "global_load_dwordx2 %0, %8, off sc0\n\t"
    "global_load_dwordx2 %1, %8, off offset:8 sc0\n\t"
    "global_load_dwordx2 %2, %8, off offset:16 sc0\n\t"
    "global_load_dwordx2 %3, %8, off offset:24 sc0\n\t"
    "global_load_dwordx2 %4, %8, off offset:32 sc0\n\t"
    "global_load_dwordx2 %5, %8, off offset:40 sc0\n\t"
    "global_load_dwordx2 %6, %8, off offset:48 sc0\n\t"
    "global_load_dwordx2 %7, %8, off offset:56 sc0\n\t"
    "s_waitcnt vmcnt(0)"
    : "=&v"(v[0]), "=&v"(v[1]), "=&v"(v[2]), "=&v"(v[3]),
      "=&v"(v[4]), "=&v"(v[5]), "=&v"(v[6]), "=&v"(v[7])
    : "v"(p)
    : "memory");
}

// ---------------- utility kernels ----------------

__global__ void zero_i32(int* p, int n){
  int i = blockIdx.x*256 + threadIdx.x;
  if (i < n) p[i] = 0;
}

// out[n*K + k] = bf16(in[k*N + n])   (in is [K][N] row-major)
__global__ void transpose_cast(const float* __restrict__ in, u16* __restrict__ out, int K, int N){
  int i = blockIdx.x*256 + threadIdx.x;
  if (i < N*K){ int n = i / K, k = i - n*K; out[i] = f2bf(in[(size_t)k*N + n]); }
}

__global__ void cast_bf(const float* __restrict__ in, u16* __restrict__ out, int n){
  int i = blockIdx.x*256 + threadIdx.x;
  if (i < n) out[i] = f2bf(in[i]);
}

__global__ void count_indeg(const int* __restrict__ dst, int* __restrict__ indeg){
  int e = blockIdx.x*256 + threadIdx.x;
  if (e < EDGES) atomicAdd(&indeg[dst[e]], 1);
}

__global__ void compute_dinv(const int* __restrict__ indeg, float* __restrict__ dinv){
  int i = blockIdx.x*256 + threadIdx.x;
  if (i < NODES) dinv[i] = rsqrtf((float)(indeg[i] + 1));  // +1 self loop
}

// single-block exclusive scan of indeg -> row_ptr (+cursor copy). N = 32768 = 1024*32
__global__ __launch_bounds__(1024) void scan_csr(const int* __restrict__ indeg,
                                                 int* __restrict__ row_ptr,
                                                 int* __restrict__ cursor){
  __shared__ int part[1024];
  int tid = threadIdx.x, base = tid*32;
  int loc[32]; int s = 0;
  for (int i=0;i<32;i++){ loc[i] = s; s += indeg[base+i]; }
  part[tid] = s; __syncthreads();
  for (int off=1; off<1024; off<<=1){
    int v = part[tid]; int add = (tid>=off) ? part[tid-off] : 0;
    __syncthreads(); part[tid] = v + add; __syncthreads();
  }
  int offt = (tid==0) ? 0 : part[tid-1];
  for (int i=0;i<32;i++){ int v = offt + loc[i]; row_ptr[base+i] = v; cursor[base+i] = v; }
}

__global__ void fill_csr(const int* __restrict__ src, const int* __restrict__ dst,
                         int* __restrict__ cursor, int* __restrict__ csr_src){
  int e = blockIdx.x*256 + threadIdx.x;
  if (e < EDGES){ int d = dst[e]; int p = atomicAdd(&cursor[d], 1); csr_src[p] = src[e]; }
}

// ---------------- GCN aggregation ----------------
__global__ __launch_bounds__(256) void agg_emb(const int* __restrict__ x, const u16* __restrict__ embb,
    const float* __restrict__ dinv, const int* __restrict__ row_ptr, const int* __restrict__ indeg,
    const int* __restrict__ csr_src, u16* __restrict__ out){
  int node = blockIdx.x*4 + (threadIdx.x>>6);
  int lane = threadIdx.x & 63;
  float di = dinv[node];
  int xi = x[node];
  u64 hv = *(const u64*)(embb + (size_t)xi*DEMB + lane*4);
  u32 h0 = (u32)hv, h1 = (u32)(hv>>32);
  float a0 = lo16(h0)*di, a1 = hi16(h0)*di, a2 = lo16(h1)*di, a3 = hi16(h1)*di;
  int st = row_ptr[node], cn = indeg[node];
  for (int p = st; p < st+cn; p++){
    int s = csr_src[p];
    float ws = dinv[s];
    u64 v = *(const u64*)(embb + (size_t)x[s]*DEMB + lane*4);
    u32 w0 = (u32)v, w1 = (u32)(v>>32);
    a0 += lo16(w0)*ws; a1 += hi16(w0)*ws; a2 += lo16(w1)*ws; a3 += hi16(w1)*ws;
  }
  u64 pv = (u64)pack2(a0*di,a1*di) | ((u64)pack2(a2*di,a3*di)<<32);
  *(u64*)(out + (size_t)node*DEMB + lane*4) = pv;
}

__global__ __launch_bounds__(256) void agg_h(const u16* __restrict__ hin, const float* __restrict__ dinv,
    const int* __restrict__ row_ptr, const int* __restrict__ indeg,
    const int* __restrict__ csr_src, u16* __restrict__ out){
  int node = blockIdx.x*4 + (threadIdx.x>>6);
  int lane = threadIdx.x & 63;
  float di = dinv[node];
  float a[8];
  uint4 hv = *((const uint4*)(hin + (size_t)node*HDIM) + lane);
  a[0]=lo16(hv.x)*di; a[1]=hi16(hv.x)*di; a[2]=lo16(hv.y)*di; a[3]=hi16(hv.y)*di;
  a[4]=lo16(hv.z)*di; a[5]=hi16(hv.z)*di; a[6]=lo16(hv.w)*di; a[7]=hi16(hv.w)*di;
  int st = row_ptr[node], cn = indeg[node];
  for (int p = st; p < st+cn; p++){
    int s = csr_src[p];
    float ws = dinv[s];
    uint4 v = *((const uint4*)(hin + (size_t)s*HDIM) + lane);
    a[0]+=lo16(v.x)*ws; a[1]+=hi16(v.x)*ws; a[2]+=lo16(v.y)*ws; a[3]+=hi16(v.y)*ws;
    a[4]+=lo16(v.z)*ws; a[5]+=hi16(v.z)*ws; a[6]+=lo16(v.w)*ws; a[7]+=hi16(v.w)*ws;
  }
  uint4 o; o.x=pack2(a[0]*di,a[1]*di); o.y=pack2(a[2]*di,a[3]*di);
  o.z=pack2(a[4]*di,a[5]*di); o.w=pack2(a[6]*di,a[7]*di);
  *(uint4*)(out + (size_t)node*HDIM + lane*8) = o;
}

// ---------------- bf16 MFMA GEMM: C[M,N] = act(A[M,K] @ BT[N,K]^T + bias) ----------------
#define BM 128
#define BN 128
#define BKK 32
__global__ __launch_bounds__(256) void gemm_bt(const u16* __restrict__ A, const u16* __restrict__ BT,
    const float* __restrict__ bias, u16* __restrict__ C, int M, int N, int K, int relu){
  __shared__ u16 aS[BM][BKK+8];
  __shared__ u16 bS[BN][BKK+8];
  int tid = threadIdx.x;
  int m0 = blockIdx.y * BM, n0 = blockIdx.x * BN;
  int lane = tid & 63, w = tid >> 6;
  int wm = w >> 1, wn = w & 1;
  f32x4 acc[4][4];
  for (int i=0;i<4;i++) for (int j=0;j<4;j++) acc[i][j] = (f32x4)0.0f;

  int r  = tid >> 1;
  int cc = (tid & 1) * 16;
  const u16* Ag = A + (size_t)(m0 + r) * K + cc;
  const u16* Bg = BT + (size_t)(n0 + r) * K + cc;
  int l15 = lane & 15, q8 = (lane >> 4) * 8;

  for (int k0 = 0; k0 < K; k0 += BKK) {
    uint4 av0 = *(const uint4*)(Ag + k0);
    uint4 av1 = *(const uint4*)(Ag + k0 + 8);
    uint4 bv0 = *(const uint4*)(Bg + k0);
    uint4 bv1 = *(const uint4*)(Bg + k0 + 8);
    *(uint4*)&aS[r][cc]   = av0; *(uint4*)&aS[r][cc+8] = av1;
    *(uint4*)&bS[r][cc]   = bv0; *(uint4*)&bS[r][cc+8] = bv1;
    __syncthreads();
    short8 af[4], bfr[4];
    for (int i=0;i<4;i++) af[i]  = *(const short8*)&aS[wm*64 + i*16 + l15][q8];
    for (int j=0;j<4;j++) bfr[j] = *(const short8*)&bS[wn*64 + j*16 + l15][q8];
    for (int i=0;i<4;i++)
      for (int j=0;j<4;j++)
        acc[i][j] = __builtin_amdgcn_mfma_f32_16x16x32_bf16(af[i], bfr[j], acc[i][j], 0, 0, 0);
    __syncthreads();
  }
  int q = lane >> 4;
  for (int i=0;i<4;i++) for (int j=0;j<4;j++){
    int col = n0 + wn*64 + j*16 + l15;
    float bval = bias[col];
    for (int rr=0; rr<4; rr++){
      int row = m0 + wm*64 + i*16 + q*4 + rr;
      float v = acc[i][j][rr] + bval;
      if (relu) v = fmaxf(v, 0.f);
      C[(size_t)row * N + col] = f2bf(v);
    }
  }
}

// ---------------- GRU R10: XCC_ID-verified XCD-local teams, tag-in-data L2 exchange ----------------
// R8: exchange is a serial MALL-latency chain (traffic-250x cut changed nothing). R9: XCD
// placement GUESSED via blockIdx%8 -> fast path never hit; per-thread sticky fallback churned
// (occasional cap-outs at 25us/step). R10 fixes both:
//  * MEASURED placement: 256 WGs at 1/CU (122KB LDS) fill all 256 CUs -> exactly 32 WGs/XCD.
//    Each WG reads HW_REG_XCC_ID (learn_hip m09) and takes a per-XCD atomic ticket; XCDs 0-3
//    each host one team of 16 (tickets 0-15). Teams share ONE L2 by construction.
//  * Exchange = R5's proven tag-in-data u64 protocol, but through the local XCD L2: publish
//    via workgroup-scope store (write-through L1 -> local L2) + agent-scope store (MALL,
//    correctness net); poll 8 tagged u64 with sc0 loads (bypass L1, L2 hit ~0.1us RT).
//  * WG-COLLECTIVE fallback: any lane capping the fast poll sets an LDS flag; after the step
//    barrier the whole WG latches to agent-only forever (no churn). All spins capped -> a
//    protocol bug ends as wrong numbers with counters, never a dead container.
// Skew<=1 parity safety is path-mixed-safe: a reader's tag-(t+2) publish is program-ordered
// after its step-t reads (vmcnt(0) in poll) in EITHER region; writers gate on seeing t+2 from
// all 16 WGs before overwriting parity p. Numerics identical to R5 (absmax 0).
__global__ __launch_bounds__(512) void gru_kernel(const u16* __restrict__ gi,
    const float* __restrict__ Whh, const float* __restrict__ bhh,
    float* __restrict__ graph_emb, u64* __restrict__ fdb_base, u64* __restrict__ adb_base,
    int* __restrict__ tickets){
  __shared__ u16  w_lds[96*520];
  __shared__ u16  h_lds[16*520];
  __shared__ float gh_lds[16*100];
  __shared__ int  s_g, s_j, s_fail;

  int tid = threadIdx.x;
  if (tid == 0){
    u32 xcd;
    asm volatile("s_getreg_b32 %0, hwreg(HW_REG_XCC_ID)" : "=s"(xcd));
    xcd &= 7u;
    int slot = atomicAdd(&tickets[xcd], 1);
    s_g = (xcd < 4 && slot < 16) ? (int)xcd : -1;
    s_j = slot;
    s_fail = 0;
  }
  __syncthreads();
  int g = s_g, j = s_j;
  if (g < 0) return;                     // non-team WGs (XCD>=4 or ticket>=16) exit
  int wave = tid >> 6;

  // load Whh slice: rows {j*32..+32} of each gate, bf16 into LDS (padded stride 520)
  for (int idx = tid; idx < 96*512; idx += 512){
    int rr = idx >> 9, c = idx & 511;
    int grow = (rr >> 5) * 512 + j*32 + (rr & 31);
    w_lds[rr*520 + c] = f2bf(Whh[(size_t)grow*512 + c]);
  }
  for (int idx = tid; idx < 16*520; idx += 512) h_lds[idx] = 0;

  int b = tid >> 5, hh = tid & 31;     // (batch-in-group, h-in-slice)
  int bg = g*16 + b;
  int c_r = j*32 + hh, c_z = 512 + j*32 + hh, c_n = 1024 + j*32 + hh;
  float bias_r = bhh[c_r], bias_z = bhh[c_z], bias_n = bhh[c_n];
  const u16* gi_row = gi + (size_t)bg * LSEQ * 1536;
  float h_prev = 0.f, accm = 0.f;
  int l15 = tid & 15, q8 = ((tid & 63)>>4)*8, qr = ((tid & 63)>>4)*4;

  u64* fdb = fdb_base + (size_t)g * 8192;   // [parity][16 b][256 slots] u64 (fast / XCD L2)
  u64* adb = adb_base + (size_t)g * 8192;   // same layout (agent / MALL)
  u16 g_r = gi_row[c_r], g_z = gi_row[c_z], g_n = gi_row[c_n];

  bool usefast = true;

  __syncthreads();

  for (int t = 0; t < LSEQ; t++){
    u32 tag = (u32)(t + 1);
    int par = t & 1;

    // ---- matvec: gh = h @ Whh_slice^T (waves 0-5) ----
    if (wave < 6){
      f32x4 acc0 = (f32x4)0.0f, acc1 = (f32x4)0.0f;
      const u16* wrow = &w_lds[(wave*16 + l15)*520];
      const u16* hrow = &h_lds[l15*520];
      #pragma unroll
      for (int k0 = 0; k0 < 256; k0 += 32){
        acc0 = __builtin_amdgcn_mfma_f32_16x16x32_bf16(*(const short8*)(hrow + k0 + q8),
                                                       *(const short8*)(wrow + k0 + q8), acc0, 0, 0, 0);
        acc1 = __builtin_amdgcn_mfma_f32_16x16x32_bf16(*(const short8*)(hrow + 256 + k0 + q8),
                                                       *(const short8*)(wrow + 256 + k0 + q8), acc1, 0, 0, 0);
      }
      f32x4 acc = acc0 + acc1;
      int col = wave*16 + l15;
      #pragma unroll
      for (int rr2 = 0; rr2 < 4; rr2++) gh_lds[(qr + rr2)*100 + col] = acc[rr2];
    }
    __syncthreads();                       // B1: gh ready

    // ---- gates ----
    float ghr = gh_lds[b*100 + hh]      + bias_r;
    float ghz = gh_lds[b*100 + 32 + hh] + bias_z;
    float ghn = gh_lds[b*100 + 64 + hh] + bias_n;
    float rg = 1.f / (1.f + __expf(-(bf2f(g_r) + ghr)));
    float zg = 1.f / (1.f + __expf(-(bf2f(g_z) + ghz)));
    float pre = bf2f(g_n) + rg * ghn;
    pre = fminf(fmaxf(pre, -20.f), 20.f);
    float e2 = __expf(2.f * pre);
    float nn = (e2 - 1.f) / (e2 + 1.f);
    float h_new = (1.f - zg) * nn + zg * h_prev;
    accm += h_new; h_prev = h_new;

    // ---- dual publish: tagged u64, even lanes (fire-and-forget) ----
    float h_nb = __shfl_xor(h_new, 1, 64);   // partner hh^1 (same wave: lane^1)
    size_t slot = (size_t)(par*16 + b)*256 + j*16 + (hh>>1);
    if ((hh & 1) == 0){
      u64 val = ((u64)tag << 32) | (u64)pack2(h_new, h_nb);
      __hip_atomic_store(fdb + slot, val, __ATOMIC_RELAXED, __HIP_MEMORY_SCOPE_WORKGROUP); // -> local L2
      __hip_atomic_store(adb + slot, val, __ATOMIC_RELAXED, __HIP_MEMORY_SCOPE_AGENT);     // -> MALL
    }

    // prefetch next step's gate inputs (overlaps the poll)
    int tn = (t + 1 < LSEQ) ? t + 1 : t;
    const u16* gp2 = gi_row + (size_t)tn * 1536;
    u16 n_r = gp2[c_r], n_z = gp2[c_z], n_n = gp2[c_n];

    // ---- poll own 8 tagged u64: fast (same-L2 sc0) then agent (MALL) fallback ----
    size_t rowoff = (size_t)(par*16 + b)*256 + hh*8;
    const u64* rpf = fdb + rowoff;
    const u64* rpa = adb + rowoff;
    u64 v[8];
    bool got = false;
    if (usefast){
      int cap = (t < 2) ? 8192 : 512;      // generous: L2 RT ~0.1us; t<2 absorbs startup skew
      for (int it = 0; it < cap; it++){
        poll8_sc0(rpf, v);
        bool ok = true;
        #pragma unroll
        for (int i=0;i<8;i++) ok = ok && ((u32)(v[i] >> 32) == tag);
        if (ok){ got = true; break; }
      }
      if (!got) s_fail = 1;                // race-benign; whole WG latches off after barrier
    }
    if (!got){
      int spins = 0; bool ok;
      do {
        #pragma unroll
        for (int i=0;i<8;i++) v[i] = __hip_atomic_load(rpa + i, __ATOMIC_RELAXED, __HIP_MEMORY_SCOPE_AGENT);
        ok = true;
        #pragma unroll
        for (int i=0;i<8;i++) ok = ok && ((u32)(v[i] >> 32) == tag);
      } while (!ok && ++spins < 65536);    // capped: bug -> wrong numbers, never a hang
    }

    // commit 8 pairs (32 B) into h_lds row b
    u32* hl = (u32*)h_lds + b*260 + hh*8;
    #pragma unroll
    for (int i=0;i<8;i++) hl[i] = (u32)v[i];
    __syncthreads();                       // B2: h_lds ready; s_fail stores visible
    usefast = usefast && (s_fail == 0);    // WG-collective latch (sticky off)

    g_r = n_r; g_z = n_z; g_n = n_n;
  }
  graph_emb[(size_t)bg*512 + j*32 + hh] = accm * (1.f/512.f);
}

// ---------------- head: relu(g@fc1+b) @ fc2 + b -> sigmoid ----------------
__global__ __launch_bounds__(256) void head(const float* __restrict__ graph_emb, const float* __restrict__ focal,
    const float* __restrict__ fc1w, const float* __restrict__ fc1b,
    const float* __restrict__ fc2w, const float* __restrict__ fc2b, float* __restrict__ out){
  __shared__ float gv[513];
  __shared__ float h1s[512];
  __shared__ float red[4];
  int bq = blockIdx.x, tid = threadIdx.x;
  for (int i = tid; i < 512; i += 256) gv[i] = graph_emb[(size_t)bq*512 + i];
  if (tid == 0) gv[512] = focal[bq];
  __syncthreads();
  for (int c = tid; c < 512; c += 256){
    float acc = fc1b[c];
    for (int k = 0; k < 513; k++) acc += gv[k] * fc1w[(size_t)k*512 + c];
    h1s[c] = fmaxf(acc, 0.f);
  }
  __syncthreads();
  float p = h1s[tid]*fc2w[tid] + h1s[tid+256]*fc2w[tid+256];
  for (int off = 32; off; off >>= 1) p += __shfl_down(p, off, 64);
  if ((tid & 63) == 0) red[tid >> 6] = p;
  __syncthreads();
  if (tid == 0){
    float s = red[0]+red[1]+red[2]+red[3] + fc2b[0];
    out[bq] = 1.f / (1.f + __expf(-s));
  }
}

// ---------------- launch ----------------
extern "C" void kernel_launch(void* const* d_in, const int* in_sizes, int n_in,
                              void* d_out, int out_size, void* d_ws, size_t ws_size,
                              hipStream_t stream){
  const int*   x     = (const int*)d_in[0];
  const int*   edge  = (const int*)d_in[1];
  const int*   srcp  = edge;
  const int*   dstp  = edge + EDGES;
  const float* focal = (const float*)d_in[3];
  const float* emb   = (const float*)d_in[4];
  const float* W1    = (const float*)d_in[5];
  const float* b1    = (const float*)d_in[6];
  const float* W2    = (const float*)d_in[7];
  const float* b2    = (const float*)d_in[8];
  const float* Wih   = (const float*)d_in[9];
  const float* Whh   = (const float*)d_in[10];
  const float* bih   = (const float*)d_in[11];
  const float* bhh   = (const float*)d_in[12];
  const float* fc1w  = (const float*)d_in[13];
  const float* fc1b  = (const float*)d_in[14];
  const float* fc2w  = (const float*)d_in[15];
  const float* fc2b  = (const float*)d_in[16];

  char* ws = (char*)d_ws;
  constexpr size_t H2_OFF    = 0;                      // 32 MB
  constexpr size_t AGG1_OFF  = 33554432;               // 16 MB
  constexpr size_t H1_OFF    = 50331648;               // 32 MB
  constexpr size_t AGG2_OFF  = 83886080;               // 32 MB (embb lives here until agg_h)
  constexpr size_t GI_OFF    = 33554432;               // 96 MB (after aggs dead)
  constexpr size_t MISC      = 134217728;
  constexpr size_t INDEG_OFF = MISC;
  constexpr size_t DINV_OFF  = MISC + 131328;
  constexpr size_t ROWPTR_OFF= MISC + 262400;
  constexpr size_t CURSOR_OFF= MISC + 393472;
  constexpr size_t CSR_OFF   = MISC + 524544;
  constexpr size_t W1T_OFF   = MISC + 2621696;
  constexpr size_t W2T_OFF   = MISC + 2883840;
  constexpr size_t WIHB_OFF  = MISC + 3408128;
  constexpr size_t XBUF_OFF  = MISC + 4980992;         // fast region: 4 teams x 8192 u64 = 256 KB
  constexpr size_t XBUF2_OFF = MISC + 5243136;         // agent region: 256 KB
  constexpr size_t TICK_OFF  = MISC + 5505280;         // 8 ints (pad 256 B)
  constexpr size_t GEMB_OFF  = MISC + 5505536;

  int*   indeg  = (int*)(ws + INDEG_OFF);
  float* dinv   = (float*)(ws + DINV_OFF);
  int*   rowptr = (int*)(ws + ROWPTR_OFF);
  int*   cursor = (int*)(ws + CURSOR_OFF);
  int*   csrsrc = (int*)(ws + CSR_OFF);
  u16*   W1T    = (u16*)(ws + W1T_OFF);
  u16*   W2T    = (u16*)(ws + W2T_OFF);
  u16*   WihB   = (u16*)(ws + WIHB_OFF);
  u16*   agg1   = (u16*)(ws + AGG1_OFF);
  u16*   h1     = (u16*)(ws + H1_OFF);
  u16*   agg2   = (u16*)(ws + AGG2_OFF);
  u16*   embb   = (u16*)(ws + AGG2_OFF);               // dead before agg_h writes agg2
  u16*   h2     = (u16*)(ws + H2_OFF);
  u16*   gi     = (u16*)(ws + GI_OFF);
  u64*   fdb    = (u64*)(ws + XBUF_OFF);
  u64*   adb    = (u64*)(ws + XBUF2_OFF);
  int*   ticks  = (int*)(ws + TICK_OFF);
  float* gemb   = (float*)(ws + GEMB_OFF);

  zero_i32<<<129, 256, 0, stream>>>(indeg, 32768 + 64);
  zero_i32<<<1, 256, 0, stream>>>(ticks, 64);
  transpose_cast<<<512, 256, 0, stream>>>(W1, W1T, 256, 512);
  transpose_cast<<<1024, 256, 0, stream>>>(W2, W2T, 512, 512);
  cast_bf<<<3072, 256, 0, stream>>>(Wih, WihB, 1536*512);
  cast_bf<<<10000, 256, 0, stream>>>(emb, embb, 10000*256);
  count_indeg<<<2048, 256, 0, stream>>>(dstp, indeg);
  compute_dinv<<<128, 256, 0, stream>>>(indeg, dinv);
  scan_csr<<<1, 1024, 0, stream>>>(indeg, rowptr, cursor);
  fill_csr<<<2048, 256, 0, stream>>>(srcp, dstp, cursor, csrsrc);
  agg_emb<<<8192, 256, 0, stream>>>(x, embb, dinv, rowptr, indeg, csrsrc, agg1);
  gemm_bt<<<dim3(4, 256), 256, 0, stream>>>(agg1, W1T, b1, h1, NODES, 512, 256, 1);
  agg_h<<<8192, 256, 0, stream>>>(h1, dinv, rowptr, indeg, csrsrc, agg2);
  gemm_bt<<<dim3(4, 256), 256, 0, stream>>>(agg2, W2T, b2, h2, NODES, 512, 512, 1);
  gemm_bt<<<dim3(12, 256), 256, 0, stream>>>(h2, WihB, bih, gi, NODES, 1536, 512, 0);
  gru_kernel<<<256, 512, 0, stream>>>(gi, Whh, bhh, gemb, fdb, adb, ticks);
  head<<<64, 256, 0, stream>>>(gemb, focal, fc1w, fc1b, fc2w, fc2b, (float*)d_out);
}

// Round 6
// 2890.595 us; speedup vs baseline: 3.3046x; 3.1954x over previous
//
#include <hip/hip_runtime.h>

#define NODES 32768
#define EDGES 524288
#define BGR   64
#define LSEQ  512
#define DEMB  256
#define HDIM  512

typedef unsigned short u16;
typedef unsigned int   u32;
typedef unsigned long long u64;
typedef __attribute__((ext_vector_type(8))) short short8;
typedef __attribute__((ext_vector_type(4))) float f32x4;

__device__ __forceinline__ float bf2f(u16 u){ u32 x = ((u32)u)<<16; float f; __builtin_memcpy(&f,&x,4); return f; }
__device__ __forceinline__ u16 f2bf(float f){ u32 x; __builtin_memcpy(&x,&f,4); u32 r = x + 0x7fffu + ((x>>16)&1u); return (u16)(r>>16); }
__device__ __forceinline__ float lo16(u32 u){ u32 x = u<<16; float f; __builtin_memcpy(&f,&x,4); return f; }
__device__ __forceinline__ float hi16(u32 u){ u32 x = u & 0xffff0000u; float f; __builtin_memcpy(&f,&x,4); return f; }
__device__ __forceinline__ u32 pack2(float a, float b){ return (u32)f2bf(a) | ((u32)f2bf(b)<<16); }

// ---------------- utility kernels ----------------

__global__ void zero_i32(int* p, int n){
  int i = blockIdx.x*256 + threadIdx.x;
  if (i < n) p[i] = 0;
}

// out[n*K + k] = bf16(in[k*N + n])   (in is [K][N] row-major)
__global__ void transpose_cast(const float* __restrict__ in, u16* __restrict__ out, int K, int N){
  int i = blockIdx.x*256 + threadIdx.x;
  if (i < N*K){ int n = i / K, k = i - n*K; out[i] = f2bf(in[(size_t)k*N + n]); }
}

__global__ void cast_bf(const float* __restrict__ in, u16* __restrict__ out, int n){
  int i = blockIdx.x*256 + threadIdx.x;
  if (i < n) out[i] = f2bf(in[i]);
}

__global__ void count_indeg(const int* __restrict__ dst, int* __restrict__ indeg){
  int e = blockIdx.x*256 + threadIdx.x;
  if (e < EDGES) atomicAdd(&indeg[dst[e]], 1);
}

__global__ void compute_dinv(const int* __restrict__ indeg, float* __restrict__ dinv){
  int i = blockIdx.x*256 + threadIdx.x;
  if (i < NODES) dinv[i] = rsqrtf((float)(indeg[i] + 1));  // +1 self loop
}

// single-block exclusive scan of indeg -> row_ptr (+cursor copy). N = 32768 = 1024*32
__global__ __launch_bounds__(1024) void scan_csr(const int* __restrict__ indeg,
                                                 int* __restrict__ row_ptr,
                                                 int* __restrict__ cursor){
  __shared__ int part[1024];
  int tid = threadIdx.x, base = tid*32;
  int loc[32]; int s = 0;
  for (int i=0;i<32;i++){ loc[i] = s; s += indeg[base+i]; }
  part[tid] = s; __syncthreads();
  for (int off=1; off<1024; off<<=1){
    int v = part[tid]; int add = (tid>=off) ? part[tid-off] : 0;
    __syncthreads(); part[tid] = v + add; __syncthreads();
  }
  int offt = (tid==0) ? 0 : part[tid-1];
  for (int i=0;i<32;i++){ int v = offt + loc[i]; row_ptr[base+i] = v; cursor[base+i] = v; }
}

__global__ void fill_csr(const int* __restrict__ src, const int* __restrict__ dst,
                         int* __restrict__ cursor, int* __restrict__ csr_src){
  int e = blockIdx.x*256 + threadIdx.x;
  if (e < EDGES){ int d = dst[e]; int p = atomicAdd(&cursor[d], 1); csr_src[p] = src[e]; }
}

// ---------------- GCN aggregation ----------------
__global__ __launch_bounds__(256) void agg_emb(const int* __restrict__ x, const u16* __restrict__ embb,
    const float* __restrict__ dinv, const int* __restrict__ row_ptr, const int* __restrict__ indeg,
    const int* __restrict__ csr_src, u16* __restrict__ out){
  int node = blockIdx.x*4 + (threadIdx.x>>6);
  int lane = threadIdx.x & 63;
  float di = dinv[node];
  int xi = x[node];
  u64 hv = *(const u64*)(embb + (size_t)xi*DEMB + lane*4);
  u32 h0 = (u32)hv, h1 = (u32)(hv>>32);
  float a0 = lo16(h0)*di, a1 = hi16(h0)*di, a2 = lo16(h1)*di, a3 = hi16(h1)*di;
  int st = row_ptr[node], cn = indeg[node];
  for (int p = st; p < st+cn; p++){
    int s = csr_src[p];
    float ws = dinv[s];
    u64 v = *(const u64*)(embb + (size_t)x[s]*DEMB + lane*4);
    u32 w0 = (u32)v, w1 = (u32)(v>>32);
    a0 += lo16(w0)*ws; a1 += hi16(w0)*ws; a2 += lo16(w1)*ws; a3 += hi16(w1)*ws;
  }
  u64 pv = (u64)pack2(a0*di,a1*di) | ((u64)pack2(a2*di,a3*di)<<32);
  *(u64*)(out + (size_t)node*DEMB + lane*4) = pv;
}

__global__ __launch_bounds__(256) void agg_h(const u16* __restrict__ hin, const float* __restrict__ dinv,
    const int* __restrict__ row_ptr, const int* __restrict__ indeg,
    const int* __restrict__ csr_src, u16* __restrict__ out){
  int node = blockIdx.x*4 + (threadIdx.x>>6);
  int lane = threadIdx.x & 63;
  float di = dinv[node];
  float a[8];
  uint4 hv = *((const uint4*)(hin + (size_t)node*HDIM) + lane);
  a[0]=lo16(hv.x)*di; a[1]=hi16(hv.x)*di; a[2]=lo16(hv.y)*di; a[3]=hi16(hv.y)*di;
  a[4]=lo16(hv.z)*di; a[5]=hi16(hv.z)*di; a[6]=lo16(hv.w)*di; a[7]=hi16(hv.w)*di;
  int st = row_ptr[node], cn = indeg[node];
  for (int p = st; p < st+cn; p++){
    int s = csr_src[p];
    float ws = dinv[s];
    uint4 v = *((const uint4*)(hin + (size_t)s*HDIM) + lane);
    a[0]+=lo16(v.x)*ws; a[1]+=hi16(v.x)*ws; a[2]+=lo16(v.y)*ws; a[3]+=hi16(v.y)*ws;
    a[4]+=lo16(v.z)*ws; a[5]+=hi16(v.z)*ws; a[6]+=lo16(v.w)*ws; a[7]+=hi16(v.w)*ws;
  }
  uint4 o; o.x=pack2(a[0]*di,a[1]*di); o.y=pack2(a[2]*di,a[3]*di);
  o.z=pack2(a[4]*di,a[5]*di); o.w=pack2(a[6]*di,a[7]*di);
  *(uint4*)(out + (size_t)node*HDIM + lane*8) = o;
}

// ---------------- bf16 MFMA GEMM: C[M,N] = act(A[M,K] @ BT[N,K]^T + bias) ----------------
#define BM 128
#define BN 128
#define BKK 32
__global__ __launch_bounds__(256) void gemm_bt(const u16* __restrict__ A, const u16* __restrict__ BT,
    const float* __restrict__ bias, u16* __restrict__ C, int M, int N, int K, int relu){
  __shared__ u16 aS[BM][BKK+8];
  __shared__ u16 bS[BN][BKK+8];
  int tid = threadIdx.x;
  int m0 = blockIdx.y * BM, n0 = blockIdx.x * BN;
  int lane = tid & 63, w = tid >> 6;
  int wm = w >> 1, wn = w & 1;
  f32x4 acc[4][4];
  for (int i=0;i<4;i++) for (int j=0;j<4;j++) acc[i][j] = (f32x4)0.0f;

  int r  = tid >> 1;
  int cc = (tid & 1) * 16;
  const u16* Ag = A + (size_t)(m0 + r) * K + cc;
  const u16* Bg = BT + (size_t)(n0 + r) * K + cc;
  int l15 = lane & 15, q8 = (lane >> 4) * 8;

  for (int k0 = 0; k0 < K; k0 += BKK) {
    uint4 av0 = *(const uint4*)(Ag + k0);
    uint4 av1 = *(const uint4*)(Ag + k0 + 8);
    uint4 bv0 = *(const uint4*)(Bg + k0);
    uint4 bv1 = *(const uint4*)(Bg + k0 + 8);
    *(uint4*)&aS[r][cc]   = av0; *(uint4*)&aS[r][cc+8] = av1;
    *(uint4*)&bS[r][cc]   = bv0; *(uint4*)&bS[r][cc+8] = bv1;
    __syncthreads();
    short8 af[4], bfr[4];
    for (int i=0;i<4;i++) af[i]  = *(const short8*)&aS[wm*64 + i*16 + l15][q8];
    for (int j=0;j<4;j++) bfr[j] = *(const short8*)&bS[wn*64 + j*16 + l15][q8];
    for (int i=0;i<4;i++)
      for (int j=0;j<4;j++)
        acc[i][j] = __builtin_amdgcn_mfma_f32_16x16x32_bf16(af[i], bfr[j], acc[i][j], 0, 0, 0);
    __syncthreads();
  }
  int q = lane >> 4;
  for (int i=0;i<4;i++) for (int j=0;j<4;j++){
    int col = n0 + wn*64 + j*16 + l15;
    float bval = bias[col];
    for (int rr=0; rr<4; rr++){
      int row = m0 + wm*64 + i*16 + q*4 + rr;
      float v = acc[i][j][rr] + bval;
      if (relu) v = fmaxf(v, 0.f);
      C[(size_t)row * N + col] = f2bf(v);
    }
  }
}

// ---------------- GRU R11: ticket-verified same-XCD teams + R5's proven agent exchange ----------------
// Decisive locality experiment. Evidence so far: R8 (250x poll-traffic cut, neutral) -> exchange
// is a serial latency chain, not throughput. R9/R10 -> fast-L2 polling via sc0 never sees
// workgroup-scope stores even with verified same-XCD placement (R10 teams formed correctly,
// absmax=0): on gfx950 {sc1,sc0} encode SCOPE, and sc0-only (workgroup) loads can be served
// from the reader's stale L1 forever. So drop the custom cache-op path entirely.
// R11 = R5's shipped agent-scope tag-in-data protocol, verbatim, but with teams placed on ONE
// XCD via the R10 ticket mechanism (HW_REG_XCC_ID + per-XCD atomicAdd). If the fabric services
// agent ops from the local XCD L2 when the line is dirty-local, the per-step chain collapses
// (~4us -> ~1-1.5us). If agent ops are constant-cost, this lands at R5's 2.07ms and the
// exchange-latency line is exhausted. Either way: protocol proven (R5/R8/R10 all absmax=0),
// spins capped (emergency valve), no churn modes, worst case == R5.
__global__ __launch_bounds__(512) void gru_kernel(const u16* __restrict__ gi,
    const float* __restrict__ Whh, const float* __restrict__ bhh,
    float* __restrict__ graph_emb, u64* __restrict__ xbuf,
    int* __restrict__ tickets){
  __shared__ u16  w_lds[96*520];
  __shared__ u16  h_lds[16*520];
  __shared__ float gh_lds[16*100];
  __shared__ int  s_g, s_j;

  int tid = threadIdx.x;
  if (tid == 0){
    u32 xcd;
    asm volatile("s_getreg_b32 %0, hwreg(HW_REG_XCC_ID)" : "=s"(xcd));
    xcd &= 7u;
    int slot = atomicAdd(&tickets[xcd], 1);
    s_g = (xcd < 4 && slot < 16) ? (int)xcd : -1;
    s_j = slot;
  }
  __syncthreads();
  int g = s_g, j = s_j;
  if (g < 0) return;                     // non-team WGs (XCD>=4 or ticket>=16) exit
  int wave = tid >> 6;

  // load Whh slice: rows {j*32..+32} of each gate, bf16 into LDS (padded stride 520)
  for (int idx = tid; idx < 96*512; idx += 512){
    int rr = idx >> 9, c = idx & 511;
    int grow = (rr >> 5) * 512 + j*32 + (rr & 31);
    w_lds[rr*520 + c] = f2bf(Whh[(size_t)grow*512 + c]);
  }
  for (int idx = tid; idx < 16*520; idx += 512) h_lds[idx] = 0;

  int b = tid >> 5, hh = tid & 31;     // (batch-in-group, h-in-slice)
  int bg = g*16 + b;
  int c_r = j*32 + hh, c_z = 512 + j*32 + hh, c_n = 1024 + j*32 + hh;
  float bias_r = bhh[c_r], bias_z = bhh[c_z], bias_n = bhh[c_n];
  const u16* gi_row = gi + (size_t)bg * LSEQ * 1536;
  float h_prev = 0.f, accm = 0.f;
  int l15 = tid & 15, q8 = ((tid & 63)>>4)*8, qr = ((tid & 63)>>4)*4;

  u64* xb = xbuf + (size_t)g * 8192;   // [parity][16 b][256 slots] u64 (agent scope)
  u16 g_r = gi_row[c_r], g_z = gi_row[c_z], g_n = gi_row[c_n];

  __syncthreads();

  for (int t = 0; t < LSEQ; t++){
    u32 tag = (u32)(t + 1);
    int par = t & 1;

    // ---- matvec: gh = h @ Whh_slice^T (waves 0-5) ----
    if (wave < 6){
      f32x4 acc0 = (f32x4)0.0f, acc1 = (f32x4)0.0f;
      const u16* wrow = &w_lds[(wave*16 + l15)*520];
      const u16* hrow = &h_lds[l15*520];
      #pragma unroll
      for (int k0 = 0; k0 < 256; k0 += 32){
        acc0 = __builtin_amdgcn_mfma_f32_16x16x32_bf16(*(const short8*)(hrow + k0 + q8),
                                                       *(const short8*)(wrow + k0 + q8), acc0, 0, 0, 0);
        acc1 = __builtin_amdgcn_mfma_f32_16x16x32_bf16(*(const short8*)(hrow + 256 + k0 + q8),
                                                       *(const short8*)(wrow + 256 + k0 + q8), acc1, 0, 0, 0);
      }
      f32x4 acc = acc0 + acc1;
      int col = wave*16 + l15;
      #pragma unroll
      for (int rr2 = 0; rr2 < 4; rr2++) gh_lds[(qr + rr2)*100 + col] = acc[rr2];
    }
    __syncthreads();                       // B1: gh ready

    // ---- gates ----
    float ghr = gh_lds[b*100 + hh]      + bias_r;
    float ghz = gh_lds[b*100 + 32 + hh] + bias_z;
    float ghn = gh_lds[b*100 + 64 + hh] + bias_n;
    float rg = 1.f / (1.f + __expf(-(bf2f(g_r) + ghr)));
    float zg = 1.f / (1.f + __expf(-(bf2f(g_z) + ghz)));
    float pre = bf2f(g_n) + rg * ghn;
    pre = fminf(fmaxf(pre, -20.f), 20.f);
    float e2 = __expf(2.f * pre);
    float nn = (e2 - 1.f) / (e2 + 1.f);
    float h_new = (1.f - zg) * nn + zg * h_prev;
    accm += h_new; h_prev = h_new;

    // ---- publish: tagged u64, relaxed agent-scope atomic store (fire-and-forget) ----
    float h_nb = __shfl_xor(h_new, 1, 64);   // partner hh^1 (same wave: lane^1)
    if ((hh & 1) == 0){
      u64 val = ((u64)tag << 32) | (u64)pack2(h_new, h_nb);
      __hip_atomic_store(xb + (size_t)(par*16 + b)*256 + j*16 + (hh>>1), val,
                         __ATOMIC_RELAXED, __HIP_MEMORY_SCOPE_AGENT);
    }

    // prefetch next step's gate inputs (overlaps the poll)
    int tn = (t + 1 < LSEQ) ? t + 1 : t;
    const u16* gp2 = gi_row + (size_t)tn * 1536;
    u16 n_r = gp2[c_r], n_z = gp2[c_z], n_n = gp2[c_n];

    // poll own 8 tagged u64 (64 B) — detection IS the refill (R5 protocol, capped)
    const u64* rp = xb + (size_t)(par*16 + b)*256 + hh*8;
    u64 v[8];
    int spins = 0; bool ok;
    do {
      #pragma unroll
      for (int i=0;i<8;i++) v[i] = __hip_atomic_load(rp + i, __ATOMIC_RELAXED, __HIP_MEMORY_SCOPE_AGENT);
      ok = true;
      #pragma unroll
      for (int i=0;i<8;i++) ok = ok && ((u32)(v[i] >> 32) == tag);
    } while (!ok && ++spins < 16384);      // emergency valve: bug -> wrong numbers, never a hang

    // commit 8 pairs (32 B) into h_lds row b
    u32* hl = (u32*)h_lds + b*260 + hh*8;
    #pragma unroll
    for (int i=0;i<8;i++) hl[i] = (u32)v[i];
    __syncthreads();                       // B2: h_lds ready for next matvec

    g_r = n_r; g_z = n_z; g_n = n_n;
  }
  graph_emb[(size_t)bg*512 + j*32 + hh] = accm * (1.f/512.f);
}

// ---------------- head: relu(g@fc1+b) @ fc2 + b -> sigmoid ----------------
__global__ __launch_bounds__(256) void head(const float* __restrict__ graph_emb, const float* __restrict__ focal,
    const float* __restrict__ fc1w, const float* __restrict__ fc1b,
    const float* __restrict__ fc2w, const float* __restrict__ fc2b, float* __restrict__ out){
  __shared__ float gv[513];
  __shared__ float h1s[512];
  __shared__ float red[4];
  int bq = blockIdx.x, tid = threadIdx.x;
  for (int i = tid; i < 512; i += 256) gv[i] = graph_emb[(size_t)bq*512 + i];
  if (tid == 0) gv[512] = focal[bq];
  __syncthreads();
  for (int c = tid; c < 512; c += 256){
    float acc = fc1b[c];
    for (int k = 0; k < 513; k++) acc += gv[k] * fc1w[(size_t)k*512 + c];
    h1s[c] = fmaxf(acc, 0.f);
  }
  __syncthreads();
  float p = h1s[tid]*fc2w[tid] + h1s[tid+256]*fc2w[tid+256];
  for (int off = 32; off; off >>= 1) p += __shfl_down(p, off, 64);
  if ((tid & 63) == 0) red[tid >> 6] = p;
  __syncthreads();
  if (tid == 0){
    float s = red[0]+red[1]+red[2]+red[3] + fc2b[0];
    out[bq] = 1.f / (1.f + __expf(-s));
  }
}

// ---------------- launch ----------------
extern "C" void kernel_launch(void* const* d_in, const int* in_sizes, int n_in,
                              void* d_out, int out_size, void* d_ws, size_t ws_size,
                              hipStream_t stream){
  const int*   x     = (const int*)d_in[0];
  const int*   edge  = (const int*)d_in[1];
  const int*   srcp  = edge;
  const int*   dstp  = edge + EDGES;
  const float* focal = (const float*)d_in[3];
  const float* emb   = (const float*)d_in[4];
  const float* W1    = (const float*)d_in[5];
  const float* b1    = (const float*)d_in[6];
  const float* W2    = (const float*)d_in[7];
  const float* b2    = (const float*)d_in[8];
  const float* Wih   = (const float*)d_in[9];
  const float* Whh   = (const float*)d_in[10];
  const float* bih   = (const float*)d_in[11];
  const float* bhh   = (const float*)d_in[12];
  const float* fc1w  = (const float*)d_in[13];
  const float* fc1b  = (const float*)d_in[14];
  const float* fc2w  = (const float*)d_in[15];
  const float* fc2b  = (const float*)d_in[16];

  char* ws = (char*)d_ws;
  constexpr size_t H2_OFF    = 0;                      // 32 MB
  constexpr size_t AGG1_OFF  = 33554432;               // 16 MB
  constexpr size_t H1_OFF    = 50331648;               // 32 MB
  constexpr size_t AGG2_OFF  = 83886080;               // 32 MB (embb lives here until agg_h)
  constexpr size_t GI_OFF    = 33554432;               // 96 MB (after aggs dead)
  constexpr size_t MISC      = 134217728;
  constexpr size_t INDEG_OFF = MISC;
  constexpr size_t DINV_OFF  = MISC + 131328;
  constexpr size_t ROWPTR_OFF= MISC + 262400;
  constexpr size_t CURSOR_OFF= MISC + 393472;
  constexpr size_t CSR_OFF   = MISC + 524544;
  constexpr size_t W1T_OFF   = MISC + 2621696;
  constexpr size_t W2T_OFF   = MISC + 2883840;
  constexpr size_t WIHB_OFF  = MISC + 3408128;
  constexpr size_t XBUF_OFF  = MISC + 4980992;         // 4 teams x 8192 u64 = 256 KB
  constexpr size_t TICK_OFF  = MISC + 5243136;         // 8 ints (pad 256 B)
  constexpr size_t GEMB_OFF  = MISC + 5243392;

  int*   indeg  = (int*)(ws + INDEG_OFF);
  float* dinv   = (float*)(ws + DINV_OFF);
  int*   rowptr = (int*)(ws + ROWPTR_OFF);
  int*   cursor = (int*)(ws + CURSOR_OFF);
  int*   csrsrc = (int*)(ws + CSR_OFF);
  u16*   W1T    = (u16*)(ws + W1T_OFF);
  u16*   W2T    = (u16*)(ws + W2T_OFF);
  u16*   WihB   = (u16*)(ws + WIHB_OFF);
  u16*   agg1   = (u16*)(ws + AGG1_OFF);
  u16*   h1     = (u16*)(ws + H1_OFF);
  u16*   agg2   = (u16*)(ws + AGG2_OFF);
  u16*   embb   = (u16*)(ws + AGG2_OFF);               // dead before agg_h writes agg2
  u16*   h2     = (u16*)(ws + H2_OFF);
  u16*   gi     = (u16*)(ws + GI_OFF);
  u64*   xbuf   = (u64*)(ws + XBUF_OFF);
  int*   ticks  = (int*)(ws + TICK_OFF);
  float* gemb   = (float*)(ws + GEMB_OFF);

  zero_i32<<<129, 256, 0, stream>>>(indeg, 32768 + 64);
  zero_i32<<<1, 256, 0, stream>>>(ticks, 64);
  transpose_cast<<<512, 256, 0, stream>>>(W1, W1T, 256, 512);
  transpose_cast<<<1024, 256, 0, stream>>>(W2, W2T, 512, 512);
  cast_bf<<<3072, 256, 0, stream>>>(Wih, WihB, 1536*512);
  cast_bf<<<10000, 256, 0, stream>>>(emb, embb, 10000*256);
  count_indeg<<<2048, 256, 0, stream>>>(dstp, indeg);
  compute_dinv<<<128, 256, 0, stream>>>(indeg, dinv);
  scan_csr<<<1, 1024, 0, stream>>>(indeg, rowptr, cursor);
  fill_csr<<<2048, 256, 0, stream>>>(srcp, dstp, cursor, csrsrc);
  agg_emb<<<8192, 256, 0, stream>>>(x, embb, dinv, rowptr, indeg, csrsrc, agg1);
  gemm_bt<<<dim3(4, 256), 256, 0, stream>>>(agg1, W1T, b1, h1, NODES, 512, 256, 1);
  agg_h<<<8192, 256, 0, stream>>>(h1, dinv, rowptr, indeg, csrsrc, agg2);
  gemm_bt<<<dim3(4, 256), 256, 0, stream>>>(agg2, W2T, b2, h2, NODES, 512, 512, 1);
  gemm_bt<<<dim3(12, 256), 256, 0, stream>>>(h2, WihB, bih, gi, NODES, 1536, 512, 0);
  gru_kernel<<<256, 512, 0, stream>>>(gi, Whh, bhh, gemb, xbuf, ticks);
  head<<<64, 256, 0, stream>>>(gemb, focal, fc1w, fc1b, fc2w, fc2b, (float*)d_out);
}

// Round 7
// 2570.209 us; speedup vs baseline: 3.7165x; 1.1247x over previous
//
#include <hip/hip_runtime.h>

#define NODES 32768
#define EDGES 524288
#define BGR   64
#define LSEQ  512
#define DEMB  256
#define HDIM  512

typedef unsigned short u16;
typedef unsigned int   u32;
typedef unsigned long long u64;
typedef __attribute__((ext_vector_type(8))) short short8;
typedef __attribute__((ext_vector_type(4))) float f32x4;

__device__ __forceinline__ float bf2f(u16 u){ u32 x = ((u32)u)<<16; float f; __builtin_memcpy(&f,&x,4); return f; }
__device__ __forceinline__ u16 f2bf(float f){ u32 x; __builtin_memcpy(&x,&f,4); u32 r = x + 0x7fffu + ((x>>16)&1u); return (u16)(r>>16); }
__device__ __forceinline__ float lo16(u32 u){ u32 x = u<<16; float f; __builtin_memcpy(&f,&x,4); return f; }
__device__ __forceinline__ float hi16(u32 u){ u32 x = u & 0xffff0000u; float f; __builtin_memcpy(&f,&x,4); return f; }
__device__ __forceinline__ u32 pack2(float a, float b){ return (u32)f2bf(a) | ((u32)f2bf(b)<<16); }

// ---------------- utility kernels ----------------

__global__ void zero_i32(int* p, int n){
  int i = blockIdx.x*256 + threadIdx.x;
  if (i < n) p[i] = 0;
}

// out[n*K + k] = bf16(in[k*N + n])   (in is [K][N] row-major)
__global__ void transpose_cast(const float* __restrict__ in, u16* __restrict__ out, int K, int N){
  int i = blockIdx.x*256 + threadIdx.x;
  if (i < N*K){ int n = i / K, k = i - n*K; out[i] = f2bf(in[(size_t)k*N + n]); }
}

__global__ void cast_bf(const float* __restrict__ in, u16* __restrict__ out, int n){
  int i = blockIdx.x*256 + threadIdx.x;
  if (i < n) out[i] = f2bf(in[i]);
}

__global__ void count_indeg(const int* __restrict__ dst, int* __restrict__ indeg){
  int e = blockIdx.x*256 + threadIdx.x;
  if (e < EDGES) atomicAdd(&indeg[dst[e]], 1);
}

__global__ void compute_dinv(const int* __restrict__ indeg, float* __restrict__ dinv){
  int i = blockIdx.x*256 + threadIdx.x;
  if (i < NODES) dinv[i] = rsqrtf((float)(indeg[i] + 1));  // +1 self loop
}

// single-block exclusive scan of indeg -> row_ptr (+cursor copy). N = 32768 = 1024*32
__global__ __launch_bounds__(1024) void scan_csr(const int* __restrict__ indeg,
                                                 int* __restrict__ row_ptr,
                                                 int* __restrict__ cursor){
  __shared__ int part[1024];
  int tid = threadIdx.x, base = tid*32;
  int loc[32]; int s = 0;
  for (int i=0;i<32;i++){ loc[i] = s; s += indeg[base+i]; }
  part[tid] = s; __syncthreads();
  for (int off=1; off<1024; off<<=1){
    int v = part[tid]; int add = (tid>=off) ? part[tid-off] : 0;
    __syncthreads(); part[tid] = v + add; __syncthreads();
  }
  int offt = (tid==0) ? 0 : part[tid-1];
  for (int i=0;i<32;i++){ int v = offt + loc[i]; row_ptr[base+i] = v; cursor[base+i] = v; }
}

__global__ void fill_csr(const int* __restrict__ src, const int* __restrict__ dst,
                         int* __restrict__ cursor, int* __restrict__ csr_src){
  int e = blockIdx.x*256 + threadIdx.x;
  if (e < EDGES){ int d = dst[e]; int p = atomicAdd(&cursor[d], 1); csr_src[p] = src[e]; }
}

// ---------------- GCN aggregation ----------------
// bf16 embedding table (precast): halves gather traffic, ~fits XCD L2.
__global__ __launch_bounds__(256) void agg_emb(const int* __restrict__ x, const u16* __restrict__ embb,
    const float* __restrict__ dinv, const int* __restrict__ row_ptr, const int* __restrict__ indeg,
    const int* __restrict__ csr_src, u16* __restrict__ out){
  int node = blockIdx.x*4 + (threadIdx.x>>6);
  int lane = threadIdx.x & 63;
  float di = dinv[node];
  int xi = x[node];
  u64 hv = *(const u64*)(embb + (size_t)xi*DEMB + lane*4);
  u32 h0 = (u32)hv, h1 = (u32)(hv>>32);
  float a0 = lo16(h0)*di, a1 = hi16(h0)*di, a2 = lo16(h1)*di, a3 = hi16(h1)*di;
  int st = row_ptr[node], cn = indeg[node];
  for (int p = st; p < st+cn; p++){
    int s = csr_src[p];
    float ws = dinv[s];
    u64 v = *(const u64*)(embb + (size_t)x[s]*DEMB + lane*4);
    u32 w0 = (u32)v, w1 = (u32)(v>>32);
    a0 += lo16(w0)*ws; a1 += hi16(w0)*ws; a2 += lo16(w1)*ws; a3 += hi16(w1)*ws;
  }
  u64 pv = (u64)pack2(a0*di,a1*di) | ((u64)pack2(a2*di,a3*di)<<32);
  *(u64*)(out + (size_t)node*DEMB + lane*4) = pv;
}

__global__ __launch_bounds__(256) void agg_h(const u16* __restrict__ hin, const float* __restrict__ dinv,
    const int* __restrict__ row_ptr, const int* __restrict__ indeg,
    const int* __restrict__ csr_src, u16* __restrict__ out){
  int node = blockIdx.x*4 + (threadIdx.x>>6);
  int lane = threadIdx.x & 63;
  float di = dinv[node];
  float a[8];
  uint4 hv = *((const uint4*)(hin + (size_t)node*HDIM) + lane);
  a[0]=lo16(hv.x)*di; a[1]=hi16(hv.x)*di; a[2]=lo16(hv.y)*di; a[3]=hi16(hv.y)*di;
  a[4]=lo16(hv.z)*di; a[5]=hi16(hv.z)*di; a[6]=lo16(hv.w)*di; a[7]=hi16(hv.w)*di;
  int st = row_ptr[node], cn = indeg[node];
  for (int p = st; p < st+cn; p++){
    int s = csr_src[p];
    float ws = dinv[s];
    uint4 v = *((const uint4*)(hin + (size_t)s*HDIM) + lane);
    a[0]+=lo16(v.x)*ws; a[1]+=hi16(v.x)*ws; a[2]+=lo16(v.y)*ws; a[3]+=hi16(v.y)*ws;
    a[4]+=lo16(v.z)*ws; a[5]+=hi16(v.z)*ws; a[6]+=lo16(v.w)*ws; a[7]+=hi16(v.w)*ws;
  }
  uint4 o; o.x=pack2(a[0]*di,a[1]*di); o.y=pack2(a[2]*di,a[3]*di);
  o.z=pack2(a[4]*di,a[5]*di); o.w=pack2(a[6]*di,a[7]*di);
  *(uint4*)(out + (size_t)node*HDIM + lane*8) = o;
}

// ---------------- bf16 MFMA GEMM: C[M,N] = act(A[M,K] @ BT[N,K]^T + bias) ----------------
#define BM 128
#define BN 128
#define BKK 32
__global__ __launch_bounds__(256) void gemm_bt(const u16* __restrict__ A, const u16* __restrict__ BT,
    const float* __restrict__ bias, u16* __restrict__ C, int M, int N, int K, int relu){
  __shared__ u16 aS[BM][BKK+8];
  __shared__ u16 bS[BN][BKK+8];
  int tid = threadIdx.x;
  int m0 = blockIdx.y * BM, n0 = blockIdx.x * BN;
  int lane = tid & 63, w = tid >> 6;
  int wm = w >> 1, wn = w & 1;
  f32x4 acc[4][4];
  for (int i=0;i<4;i++) for (int j=0;j<4;j++) acc[i][j] = (f32x4)0.0f;

  int r  = tid >> 1;
  int cc = (tid & 1) * 16;
  const u16* Ag = A + (size_t)(m0 + r) * K + cc;
  const u16* Bg = BT + (size_t)(n0 + r) * K + cc;
  int l15 = lane & 15, q8 = (lane >> 4) * 8;

  for (int k0 = 0; k0 < K; k0 += BKK) {
    uint4 av0 = *(const uint4*)(Ag + k0);
    uint4 av1 = *(const uint4*)(Ag + k0 + 8);
    uint4 bv0 = *(const uint4*)(Bg + k0);
    uint4 bv1 = *(const uint4*)(Bg + k0 + 8);
    *(uint4*)&aS[r][cc]   = av0; *(uint4*)&aS[r][cc+8] = av1;
    *(uint4*)&bS[r][cc]   = bv0; *(uint4*)&bS[r][cc+8] = bv1;
    __syncthreads();
    short8 af[4], bfr[4];
    for (int i=0;i<4;i++) af[i]  = *(const short8*)&aS[wm*64 + i*16 + l15][q8];
    for (int j=0;j<4;j++) bfr[j] = *(const short8*)&bS[wn*64 + j*16 + l15][q8];
    for (int i=0;i<4;i++)
      for (int j=0;j<4;j++)
        acc[i][j] = __builtin_amdgcn_mfma_f32_16x16x32_bf16(af[i], bfr[j], acc[i][j], 0, 0, 0);
    __syncthreads();
  }
  int q = lane >> 4;
  for (int i=0;i<4;i++) for (int j=0;j<4;j++){
    int col = n0 + wn*64 + j*16 + l15;
    float bval = bias[col];
    for (int rr=0; rr<4; rr++){
      int row = m0 + wm*64 + i*16 + q*4 + rr;
      float v = acc[i][j][rr] + bval;
      if (relu) v = fmaxf(v, 0.f);
      C[(size_t)row * N + col] = f2bf(v);
    }
  }
}

// ---------------- GRU: 4 groups x 16 WGs; WG j owns 32-wide H-slice (96 Whh rows LDS-resident) ----------------
// R5 protocol restored (best measured: 2066us). The exchange-latency floor is mapped:
// R5 4.03us/step; R8 flag+one-shot (250x less poll traffic) 4.17; R11 same-XCD teams 4.76;
// R6 2-stream marginal +1.95. The ~3us/step publish->visible->detect lag through the MALL is
// invariant to scope/placement/traffic/ordering; the H-split decomposition is forced (Whh
// 1.5MB > LDS/RF per CU; L2-streaming is per-CU-load-BW infeasible). Tag-in-data, agent-scope
// relaxed atomics; every u64 self-validating ((t+1)<<32 | bf16pair); 2-deep parity buffer;
// skew<=1 across WGs. Tags 1..512 never equal 0xAAAAAAAA ws-poison.
__global__ __launch_bounds__(512) void gru_kernel(const u16* __restrict__ gi,
    const float* __restrict__ Whh, const float* __restrict__ bhh,
    float* __restrict__ graph_emb, u64* __restrict__ xbuf){
  __shared__ u16  w_lds[96*520];
  __shared__ u16  h_lds[16*520];
  __shared__ float gh_lds[16*100];

  int tid = threadIdx.x;
  int g = blockIdx.x >> 4, j = blockIdx.x & 15;
  int lane = tid & 63, wave = tid >> 6;

  // load Whh slice: rows {j*32..+32} of each gate, bf16 into LDS (padded stride 520)
  for (int idx = tid; idx < 96*512; idx += 512){
    int rr = idx >> 9, c = idx & 511;
    int grow = (rr >> 5) * 512 + j*32 + (rr & 31);
    w_lds[rr*520 + c] = f2bf(Whh[(size_t)grow*512 + c]);
  }
  for (int idx = tid; idx < 16*520; idx += 512) h_lds[idx] = 0;

  int b = tid >> 5, hh = tid & 31;     // (batch-in-group, h-in-slice)
  int bg = g*16 + b;
  int c_r = j*32 + hh, c_z = 512 + j*32 + hh, c_n = 1024 + j*32 + hh;
  float bias_r = bhh[c_r], bias_z = bhh[c_z], bias_n = bhh[c_n];
  const u16* gi_row = gi + (size_t)bg * LSEQ * 1536;
  float h_prev = 0.f, accm = 0.f;
  int l15 = lane & 15, q8 = (lane>>4)*8, qr = (lane>>4)*4;

  u64* xb = xbuf + (size_t)g * 8192;   // [parity][16 b][256 slots] u64
  // pipeline: gate inputs for step t held in registers
  u16 g_r = gi_row[c_r], g_z = gi_row[c_z], g_n = gi_row[c_n];

  __syncthreads();

  for (int t = 0; t < LSEQ; t++){
    if (wave < 6){
      f32x4 acc0 = (f32x4)0.0f, acc1 = (f32x4)0.0f;
      const u16* wrow = &w_lds[(wave*16 + l15)*520];
      const u16* hrow = &h_lds[l15*520];
      #pragma unroll
      for (int k0 = 0; k0 < 256; k0 += 32){
        acc0 = __builtin_amdgcn_mfma_f32_16x16x32_bf16(*(const short8*)(hrow + k0 + q8),
                                                       *(const short8*)(wrow + k0 + q8), acc0, 0, 0, 0);
        acc1 = __builtin_amdgcn_mfma_f32_16x16x32_bf16(*(const short8*)(hrow + 256 + k0 + q8),
                                                       *(const short8*)(wrow + 256 + k0 + q8), acc1, 0, 0, 0);
      }
      f32x4 acc = acc0 + acc1;
      int col = wave*16 + l15;
      #pragma unroll
      for (int rr2 = 0; rr2 < 4; rr2++) gh_lds[(qr + rr2)*100 + col] = acc[rr2];
    }
    __syncthreads();

    float ghr = gh_lds[b*100 + hh]      + bias_r;
    float ghz = gh_lds[b*100 + 32 + hh] + bias_z;
    float ghn = gh_lds[b*100 + 64 + hh] + bias_n;
    float rg = 1.f / (1.f + __expf(-(bf2f(g_r) + ghr)));
    float zg = 1.f / (1.f + __expf(-(bf2f(g_z) + ghz)));
    float pre = bf2f(g_n) + rg * ghn;
    pre = fminf(fmaxf(pre, -20.f), 20.f);
    float e2 = __expf(2.f * pre);
    float nn = (e2 - 1.f) / (e2 + 1.f);
    float h_new = (1.f - zg) * nn + zg * h_prev;
    accm += h_new; h_prev = h_new;

    u32 tag = (u32)(t + 1);
    // publish: tagged u64, relaxed agent-scope atomic store (fire-and-forget)
    float h_nb = __shfl_xor(h_new, 1, 64);   // partner hh^1 (same wave: lane^1)
    if ((hh & 1) == 0){
      u64 val = ((u64)tag << 32) | (u64)pack2(h_new, h_nb);
      __hip_atomic_store(xb + (size_t)((t&1)*16 + b)*256 + j*16 + (hh>>1), val,
                         __ATOMIC_RELAXED, __HIP_MEMORY_SCOPE_AGENT);
    }

    // prefetch next step's gate inputs (overlaps the poll)
    int tn = (t + 1 < LSEQ) ? t + 1 : t;
    const u16* gp2 = gi_row + (size_t)tn * 1536;
    u16 n_r = gp2[c_r], n_z = gp2[c_z], n_n = gp2[c_n];

    // poll own 8 tagged u64 (64 B, covers slices hh/2 halves) — detection IS the refill
    const u64* rp = xb + (size_t)((t&1)*16 + b)*256 + hh*8;
    u64 v[8];
    bool ok;
    do {
      #pragma unroll
      for (int i=0;i<8;i++) v[i] = __hip_atomic_load(rp + i, __ATOMIC_RELAXED, __HIP_MEMORY_SCOPE_AGENT);
      ok = true;
      #pragma unroll
      for (int i=0;i<8;i++) ok = ok && ((u32)(v[i] >> 32) == tag);
    } while (!ok);

    // commit 8 pairs (32 B) into h_lds row b
    u32* hl = (u32*)h_lds + b*260 + hh*8;
    #pragma unroll
    for (int i=0;i<8;i++) hl[i] = (u32)v[i];
    __syncthreads();

    g_r = n_r; g_z = n_z; g_n = n_n;
  }
  graph_emb[(size_t)bg*512 + j*32 + hh] = accm * (1.f/512.f);
}

// ---------------- head: relu(g@fc1+b) @ fc2 + b -> sigmoid ----------------
__global__ __launch_bounds__(256) void head(const float* __restrict__ graph_emb, const float* __restrict__ focal,
    const float* __restrict__ fc1w, const float* __restrict__ fc1b,
    const float* __restrict__ fc2w, const float* __restrict__ fc2b, float* __restrict__ out){
  __shared__ float gv[513];
  __shared__ float h1s[512];
  __shared__ float red[4];
  int bq = blockIdx.x, tid = threadIdx.x;
  for (int i = tid; i < 512; i += 256) gv[i] = graph_emb[(size_t)bq*512 + i];
  if (tid == 0) gv[512] = focal[bq];
  __syncthreads();
  for (int c = tid; c < 512; c += 256){
    float acc = fc1b[c];
    for (int k = 0; k < 513; k++) acc += gv[k] * fc1w[(size_t)k*512 + c];
    h1s[c] = fmaxf(acc, 0.f);
  }
  __syncthreads();
  float p = h1s[tid]*fc2w[tid] + h1s[tid+256]*fc2w[tid+256];
  for (int off = 32; off; off >>= 1) p += __shfl_down(p, off, 64);
  if ((tid & 63) == 0) red[tid >> 6] = p;
  __syncthreads();
  if (tid == 0){
    float s = red[0]+red[1]+red[2]+red[3] + fc2b[0];
    out[bq] = 1.f / (1.f + __expf(-s));
  }
}

// ---------------- launch ----------------
extern "C" void kernel_launch(void* const* d_in, const int* in_sizes, int n_in,
                              void* d_out, int out_size, void* d_ws, size_t ws_size,
                              hipStream_t stream){
  const int*   x     = (const int*)d_in[0];
  const int*   edge  = (const int*)d_in[1];
  const int*   srcp  = edge;
  const int*   dstp  = edge + EDGES;
  const float* focal = (const float*)d_in[3];
  const float* emb   = (const float*)d_in[4];
  const float* W1    = (const float*)d_in[5];
  const float* b1    = (const float*)d_in[6];
  const float* W2    = (const float*)d_in[7];
  const float* b2    = (const float*)d_in[8];
  const float* Wih   = (const float*)d_in[9];
  const float* Whh   = (const float*)d_in[10];
  const float* bih   = (const float*)d_in[11];
  const float* bhh   = (const float*)d_in[12];
  const float* fc1w  = (const float*)d_in[13];
  const float* fc1b  = (const float*)d_in[14];
  const float* fc2w  = (const float*)d_in[15];
  const float* fc2b  = (const float*)d_in[16];

  char* ws = (char*)d_ws;
  constexpr size_t H2_OFF    = 0;                      // 32 MB
  constexpr size_t AGG1_OFF  = 33554432;               // 16 MB
  constexpr size_t H1_OFF    = 50331648;               // 32 MB
  constexpr size_t AGG2_OFF  = 83886080;               // 32 MB (embb lives here until agg_h)
  constexpr size_t GI_OFF    = 33554432;               // 96 MB (after aggs dead)
  constexpr size_t MISC      = 134217728;
  constexpr size_t INDEG_OFF = MISC;
  constexpr size_t CNT_OFF   = MISC + 131072;
  constexpr size_t DINV_OFF  = MISC + 131328;
  constexpr size_t ROWPTR_OFF= MISC + 262400;
  constexpr size_t CURSOR_OFF= MISC + 393472;
  constexpr size_t CSR_OFF   = MISC + 524544;
  constexpr size_t W1T_OFF   = MISC + 2621696;
  constexpr size_t W2T_OFF   = MISC + 2883840;
  constexpr size_t WIHB_OFF  = MISC + 3408128;
  constexpr size_t XBUF_OFF  = MISC + 4980992;         // 4 groups x 8192 u64 = 256 KB
  constexpr size_t GEMB_OFF  = MISC + 5243136;

  int*   indeg  = (int*)(ws + INDEG_OFF);
  float* dinv   = (float*)(ws + DINV_OFF);
  int*   rowptr = (int*)(ws + ROWPTR_OFF);
  int*   cursor = (int*)(ws + CURSOR_OFF);
  int*   csrsrc = (int*)(ws + CSR_OFF);
  u16*   W1T    = (u16*)(ws + W1T_OFF);
  u16*   W2T    = (u16*)(ws + W2T_OFF);
  u16*   WihB   = (u16*)(ws + WIHB_OFF);
  u16*   agg1   = (u16*)(ws + AGG1_OFF);
  u16*   h1     = (u16*)(ws + H1_OFF);
  u16*   agg2   = (u16*)(ws + AGG2_OFF);
  u16*   embb   = (u16*)(ws + AGG2_OFF);               // dead before agg_h writes agg2
  u16*   h2     = (u16*)(ws + H2_OFF);
  u16*   gi     = (u16*)(ws + GI_OFF);
  u64*   xbuf   = (u64*)(ws + XBUF_OFF);
  float* gemb   = (float*)(ws + GEMB_OFF);

  zero_i32<<<129, 256, 0, stream>>>(indeg, 32768 + 64);
  transpose_cast<<<512, 256, 0, stream>>>(W1, W1T, 256, 512);
  transpose_cast<<<1024, 256, 0, stream>>>(W2, W2T, 512, 512);
  cast_bf<<<3072, 256, 0, stream>>>(Wih, WihB, 1536*512);
  cast_bf<<<10000, 256, 0, stream>>>(emb, embb, 10000*256);
  count_indeg<<<2048, 256, 0, stream>>>(dstp, indeg);
  compute_dinv<<<128, 256, 0, stream>>>(indeg, dinv);
  scan_csr<<<1, 1024, 0, stream>>>(indeg, rowptr, cursor);
  fill_csr<<<2048, 256, 0, stream>>>(srcp, dstp, cursor, csrsrc);
  agg_emb<<<8192, 256, 0, stream>>>(x, embb, dinv, rowptr, indeg, csrsrc, agg1);
  gemm_bt<<<dim3(4, 256), 256, 0, stream>>>(agg1, W1T, b1, h1, NODES, 512, 256, 1);
  agg_h<<<8192, 256, 0, stream>>>(h1, dinv, rowptr, indeg, csrsrc, agg2);
  gemm_bt<<<dim3(4, 256), 256, 0, stream>>>(agg2, W2T, b2, h2, NODES, 512, 512, 1);
  gemm_bt<<<dim3(12, 256), 256, 0, stream>>>(h2, WihB, bih, gi, NODES, 1536, 512, 0);
  gru_kernel<<<64, 512, 0, stream>>>(gi, Whh, bhh, gemb, xbuf);
  head<<<64, 256, 0, stream>>>(gemb, focal, fc1w, fc1b, fc2w, fc2b, (float*)d_out);
}